// Round 8
// baseline (237.893 us; speedup 1.0000x reference)
//
#include <hip/hip_runtime.h>
#include <hip/hip_bf16.h>

#define D_MODEL 1024
#define D_STATE 16
#define L_SEQ 2048
#define B_SZ 4
#define M_ROWS (B_SZ * L_SEQ)   // 8192
#define N_CHUNK 32               // chunks per sequence
#define C_LEN 64                 // timesteps per chunk (32*64 = 2048)

typedef __attribute__((ext_vector_type(8))) short short8;
typedef __attribute__((ext_vector_type(4))) float f32x4;
typedef unsigned int u32;
typedef __attribute__((ext_vector_type(4))) u32 u32x4;

// Raw workgroup barrier: drain LDS ops only (lgkmcnt), leave vmem loads in
// flight. __syncthreads would emit vmcnt(0) and kill the prefetch pipeline.
#define BAR() asm volatile("s_waitcnt lgkmcnt(0)\n\ts_barrier" ::: "memory")

static __device__ __forceinline__ unsigned short f2bf(float f) {
    unsigned int u = __float_as_uint(f);
    unsigned int r = (u + 0x7FFFu + ((u >> 16) & 1u)) >> 16;   // RNE
    return (unsigned short)r;
}
static __device__ __forceinline__ float bf2f(unsigned short u) {
    return __uint_as_float(((unsigned int)u) << 16);
}

// ---------------- convert fp32 -> bf16 (weights) ----------------
__global__ void conv_bf16_kernel(const float* __restrict__ src,
                                 unsigned short* __restrict__ dst, int n4) {
    int i = blockIdx.x * blockDim.x + threadIdx.x;
    if (i < n4) {
        float4 v = ((const float4*)src)[i];
        ushort4 o;
        o.x = f2bf(v.x); o.y = f2bf(v.y); o.z = f2bf(v.z); o.w = f2bf(v.w);
        ((ushort4*)dst)[i] = o;
    }
}

// ---------------- LayerNorm: x (8192 x 1024) -> xn bf16 ----------------
__global__ __launch_bounds__(256) void ln_kernel(const float* __restrict__ x,
                                                 const float* __restrict__ g,
                                                 const float* __restrict__ b,
                                                 unsigned short* __restrict__ xn) {
    int row = blockIdx.x;
    int t = threadIdx.x;
    const float4* xr = (const float4*)(x + (size_t)row * D_MODEL);
    float4 v = xr[t];
    float s  = v.x + v.y + v.z + v.w;
    float ss = v.x * v.x + v.y * v.y + v.z * v.z + v.w * v.w;
    #pragma unroll
    for (int o = 32; o > 0; o >>= 1) {
        s  += __shfl_down(s,  o);
        ss += __shfl_down(ss, o);
    }
    __shared__ float sbuf[8];
    int wid = t >> 6;
    if ((t & 63) == 0) { sbuf[wid] = s; sbuf[4 + wid] = ss; }
    __syncthreads();
    float S  = sbuf[0] + sbuf[1] + sbuf[2] + sbuf[3];
    float SS = sbuf[4] + sbuf[5] + sbuf[6] + sbuf[7];
    float mu  = S * (1.0f / D_MODEL);
    float var = SS * (1.0f / D_MODEL) - mu * mu;
    float inv = rsqrtf(var + 1e-5f);
    float4 gv = ((const float4*)g)[t];
    float4 bv = ((const float4*)b)[t];
    ushort4 o;
    o.x = f2bf((v.x - mu) * inv * gv.x + bv.x);
    o.y = f2bf((v.y - mu) * inv * gv.y + bv.y);
    o.z = f2bf((v.z - mu) * inv * gv.z + bv.z);
    o.w = f2bf((v.w - mu) * inv * gv.w + bv.w);
    ((ushort4*)(xn + (size_t)row * D_MODEL))[t] = o;
}

// ---------------- GEMM1: 128x256 block, 4 waves of 64x128 ----------------
// B-only LDS staging (double-buffered, swizzled). A-fragments load DIRECT from
// global (16B/lane coalesced; A-panel is XCD-L2-resident) with distance-1
// register double-buffer. One lgkm-only barrier per BK=32 iter.
__global__ __launch_bounds__(256, 2) void gemm1_kernel(const unsigned short* __restrict__ A,
                                                       const unsigned short* __restrict__ Bt,
                                                       const float* __restrict__ bias,
                                                       unsigned short* __restrict__ u_bf,
                                                       unsigned short* __restrict__ zs) {
    __shared__ unsigned short lB[2][256 * 32];   // 16 KB x2
    const int K = D_MODEL;

    int t = threadIdx.x;
    int lane = t & 63;
    int wave = t >> 6;
    int wm = wave >> 1, wn = wave & 1;
    int m0 = blockIdx.x * 128;
    int n0 = blockIdx.y * 256;
    int row = lane & 15;
    int quad = lane >> 4;

    // B staging: thread t owns 16B slot t in each 64-row band; fetch swizzled k-chunk
    int sr = t >> 2;
    int sc = ((t & 3) ^ ((t >> 3) & 3)) * 8;
    const unsigned short* gB0 = Bt + (size_t)(n0 + sr) * K + sc;
    const unsigned short* gB1 = Bt + (size_t)(n0 + 64 + sr) * K + sc;
    const unsigned short* gB2 = Bt + (size_t)(n0 + 128 + sr) * K + sc;
    const unsigned short* gB3 = Bt + (size_t)(n0 + 192 + sr) * K + sc;

    // A-fragment direct-global pointers (per lane, 16B contiguous)
    const unsigned short* gA[4];
    #pragma unroll
    for (int i = 0; i < 4; i++)
        gA[i] = A + (size_t)(m0 + wm * 64 + i * 16 + row) * K + quad * 8;

    // B fragment read offsets (swizzled)
    int offB[8];
    #pragma unroll
    for (int j = 0; j < 8; j++) {
        int r8 = wn * 128 + j * 16 + row;
        int half = r8 >> 6, r6 = r8 & 63;
        int slot = r6 * 4 + (quad ^ ((r6 >> 1) & 3));
        offB[j] = half * 2048 + slot * 8;
    }

    f32x4 acc[4][8] = {};

    // preload iter-0 staging regs and iter-0 A fragments
    u32x4 PB[4];
    PB[0] = *(const u32x4*)gB0;
    PB[1] = *(const u32x4*)gB1;
    PB[2] = *(const u32x4*)gB2;
    PB[3] = *(const u32x4*)gB3;
    short8 a_cur[4], a_nxt[4];
    #pragma unroll
    for (int i = 0; i < 4; i++) a_cur[i] = *(const short8*)gA[i];

    for (int kk = 0; kk < K; kk += 32) {
        unsigned short* sB = lB[(kk >> 5) & 1];
        *(u32x4*)&sB[t * 8]        = PB[0];
        *(u32x4*)&sB[2048 + t * 8] = PB[1];
        *(u32x4*)&sB[4096 + t * 8] = PB[2];
        *(u32x4*)&sB[6144 + t * 8] = PB[3];
        int kn = kk + 32;
        if (kn < K) {
            PB[0] = *(const u32x4*)(gB0 + kn);
            PB[1] = *(const u32x4*)(gB1 + kn);
            PB[2] = *(const u32x4*)(gB2 + kn);
            PB[3] = *(const u32x4*)(gB3 + kn);
            #pragma unroll
            for (int i = 0; i < 4; i++) a_nxt[i] = *(const short8*)(gA[i] + kn);
        }
        BAR();
        #pragma unroll
        for (int j = 0; j < 8; j++) {
            short8 b = *(const short8*)&sB[offB[j]];
            #pragma unroll
            for (int i = 0; i < 4; i++)
                acc[i][j] = __builtin_amdgcn_mfma_f32_16x16x32_bf16(a_cur[i], b, acc[i][j], 0, 0, 0);
        }
        #pragma unroll
        for (int i = 0; i < 4; i++) a_cur[i] = a_nxt[i];
    }

    // epilogue: C/D layout col = lane&15, row = quad*4 + reg
    int col = row;
    #pragma unroll
    for (int j = 0; j < 8; j++) {
        int n = n0 + wn * 128 + j * 16 + col;
        float bs = bias[n];
        #pragma unroll
        for (int i = 0; i < 4; i++) {
            #pragma unroll
            for (int r = 0; r < 4; r++) {
                int m = m0 + wm * 64 + i * 16 + quad * 4 + r;
                float v = acc[i][j][r] + bs;
                if (n < D_MODEL) {
                    u_bf[(size_t)m * D_MODEL + n] = f2bf(v);
                } else {
                    float sv = v / (1.0f + __expf(-v));
                    zs[(size_t)m * D_MODEL + (n - D_MODEL)] = f2bf(sv);
                }
            }
        }
    }
}

// ---------------- GEMM2: 128x128 block; B-only LDS, direct A (resid+clip) ----------------
__global__ __launch_bounds__(256) void gemm2_kernel(const unsigned short* __restrict__ A,
                                                    const unsigned short* __restrict__ Bt,
                                                    const float* __restrict__ bias,
                                                    float* __restrict__ out_f,
                                                    const float* __restrict__ resid) {
    __shared__ unsigned short lB[2][128 * 32];   // 8 KB x2
    const int K = D_MODEL;

    int t = threadIdx.x;
    int lane = t & 63;
    int wave = t >> 6;
    int wm = wave >> 1, wn = wave & 1;
    int m0 = blockIdx.x * 128;
    int n0 = blockIdx.y * 128;
    int row = lane & 15;
    int quad = lane >> 4;

    int sr = t >> 2;
    int sc = ((t & 3) ^ ((t >> 3) & 3)) * 8;
    const unsigned short* gB0 = Bt + (size_t)(n0 + sr) * K + sc;
    const unsigned short* gB1 = Bt + (size_t)(n0 + 64 + sr) * K + sc;

    const unsigned short* gA[4];
    #pragma unroll
    for (int i = 0; i < 4; i++)
        gA[i] = A + (size_t)(m0 + wm * 64 + i * 16 + row) * K + quad * 8;

    int offB[4];
    #pragma unroll
    for (int j = 0; j < 4; j++) {
        int r6 = wn * 64 + j * 16 + row;
        int half = r6 >> 6, rr = r6 & 63;
        int slot = rr * 4 + (quad ^ ((rr >> 1) & 3));
        offB[j] = half * 2048 + slot * 8;
    }

    f32x4 acc[4][4] = {};

    u32x4 PB[2];
    PB[0] = *(const u32x4*)gB0;
    PB[1] = *(const u32x4*)gB1;
    short8 a_cur[4], a_nxt[4];
    #pragma unroll
    for (int i = 0; i < 4; i++) a_cur[i] = *(const short8*)gA[i];

    for (int kk = 0; kk < K; kk += 32) {
        unsigned short* sB = lB[(kk >> 5) & 1];
        *(u32x4*)&sB[t * 8]        = PB[0];
        *(u32x4*)&sB[2048 + t * 8] = PB[1];
        int kn = kk + 32;
        if (kn < K) {
            PB[0] = *(const u32x4*)(gB0 + kn);
            PB[1] = *(const u32x4*)(gB1 + kn);
            #pragma unroll
            for (int i = 0; i < 4; i++) a_nxt[i] = *(const short8*)(gA[i] + kn);
        }
        BAR();
        #pragma unroll
        for (int j = 0; j < 4; j++) {
            short8 b = *(const short8*)&sB[offB[j]];
            #pragma unroll
            for (int i = 0; i < 4; i++)
                acc[i][j] = __builtin_amdgcn_mfma_f32_16x16x32_bf16(a_cur[i], b, acc[i][j], 0, 0, 0);
        }
        #pragma unroll
        for (int i = 0; i < 4; i++) a_cur[i] = a_nxt[i];
    }

    int col = row;
    #pragma unroll
    for (int i = 0; i < 4; i++) {
        #pragma unroll
        for (int j = 0; j < 4; j++) {
            int n = n0 + wn * 64 + j * 16 + col;
            float bs = bias[n];
            #pragma unroll
            for (int r = 0; r < 4; r++) {
                int m = m0 + wm * 64 + i * 16 + quad * 4 + r;
                float y = acc[i][j][r] + bs + resid[(size_t)m * D_MODEL + n];
                y = fminf(10.0f, fmaxf(-10.0f, y));
                out_f[(size_t)m * D_MODEL + n] = y;
            }
        }
    }
}

// ---------------- chunked SSM scan (u bf16) ----------------
static __device__ __forceinline__ void load_params(const float* __restrict__ A_log,
                                                   const float* __restrict__ log_dt,
                                                   int d, float* ab, float& dt_out) {
    float dt = fminf(1.0f, fmaxf(1e-4f, __expf(log_dt[d])));
    #pragma unroll
    for (int n = 0; n < D_STATE; n++) {
        float a = __expf(-__expf(A_log[d * D_STATE + n]) * dt);
        ab[n] = fminf(1.0f - 1e-8f, fmaxf(1e-8f, a));
    }
    dt_out = dt;
}

// pass1: zero-init local scan of each chunk; writes chunk-final states.
__global__ __launch_bounds__(256) void scan1_kernel(const unsigned short* __restrict__ u,
                                                    const float* __restrict__ A_log,
                                                    const float* __restrict__ log_dt,
                                                    float* __restrict__ s_local) {
    int gid = blockIdx.x * 256 + threadIdx.x;
    int d = gid & (D_MODEL - 1);
    int c = (gid >> 10) & (N_CHUNK - 1);
    int b = gid >> 15;

    float ab[D_STATE], dt;
    load_params(A_log, log_dt, d, ab, dt);

    float s[D_STATE];
    #pragma unroll
    for (int n = 0; n < D_STATE; n++) s[n] = 0.0f;

    const unsigned short* up = u + ((size_t)(b * L_SEQ + c * C_LEN)) * D_MODEL + d;
    for (int t = 0; t < C_LEN; t++) {
        float uv = bf2f(up[(size_t)t * D_MODEL]);
        #pragma unroll
        for (int n = 0; n < D_STATE; n++) s[n] = fmaf(ab[n], s[n], uv);
    }
    float* sl = s_local + ((size_t)(b * N_CHUNK + c) * D_STATE) * D_MODEL + d;
    #pragma unroll
    for (int n = 0; n < D_STATE; n++) sl[(size_t)n * D_MODEL] = s[n];
}

// combine: sequential prefix over chunks.
__global__ __launch_bounds__(256) void scan_combine_kernel(const float* __restrict__ s_local,
                                                           const float* __restrict__ A_log,
                                                           const float* __restrict__ log_dt,
                                                           float* __restrict__ s_init) {
    int gid = blockIdx.x * 256 + threadIdx.x;
    int d = gid & (D_MODEL - 1);
    int n = (gid >> 10) & (D_STATE - 1);
    int b = gid >> 14;

    float dt = fminf(1.0f, fmaxf(1e-4f, __expf(log_dt[d])));
    float a = __expf(-__expf(A_log[d * D_STATE + n]) * dt);
    a = fminf(1.0f - 1e-8f, fmaxf(1e-8f, a));
    float aP = a;
    #pragma unroll
    for (int q = 0; q < 6; q++) aP = aP * aP;   // a^64

    float s = 0.0f;
    size_t stride_c = (size_t)D_STATE * D_MODEL;
    const float* sl = s_local + ((size_t)b * N_CHUNK * D_STATE + n) * D_MODEL + d;
    float* si = s_init + ((size_t)b * N_CHUNK * D_STATE + n) * D_MODEL + d;
    si[0] = 0.0f;
    for (int c = 1; c < N_CHUNK; c++) {
        s = fmaf(aP, s, sl[(size_t)(c - 1) * stride_c]);
        si[(size_t)c * stride_c] = s;
    }
}

// pass2: rescan with correct init; fuse y = sum_n cb_n s_n, y *= silu(z); bf16 out.
__global__ __launch_bounds__(256) void scan2_kernel(const unsigned short* __restrict__ u,
                                                    const unsigned short* __restrict__ zs,
                                                    const float* __restrict__ A_log,
                                                    const float* __restrict__ Bp,
                                                    const float* __restrict__ Cp,
                                                    const float* __restrict__ log_dt,
                                                    const float* __restrict__ s_init,
                                                    unsigned short* __restrict__ yz) {
    int gid = blockIdx.x * 256 + threadIdx.x;
    int d = gid & (D_MODEL - 1);
    int c = (gid >> 10) & (N_CHUNK - 1);
    int b = gid >> 15;

    float ab[D_STATE], dt;
    load_params(A_log, log_dt, d, ab, dt);
    float cb[D_STATE];
    #pragma unroll
    for (int n = 0; n < D_STATE; n++)
        cb[n] = Cp[d * D_STATE + n] * Bp[d * D_STATE + n] * dt;

    float s[D_STATE];
    const float* si = s_init + ((size_t)(b * N_CHUNK + c) * D_STATE) * D_MODEL + d;
    #pragma unroll
    for (int n = 0; n < D_STATE; n++) s[n] = si[(size_t)n * D_MODEL];

    size_t m0 = (size_t)(b * L_SEQ + c * C_LEN);
    const unsigned short* up = u + m0 * D_MODEL + d;
    const unsigned short* zp = zs + m0 * D_MODEL + d;
    unsigned short* yp = yz + m0 * D_MODEL + d;

    for (int t = 0; t < C_LEN; t++) {
        float uv = bf2f(up[(size_t)t * D_MODEL]);
        #pragma unroll
        for (int n = 0; n < D_STATE; n++) s[n] = fmaf(ab[n], s[n], uv);
        float y = 0.0f;
        #pragma unroll
        for (int n = 0; n < D_STATE; n++) y = fmaf(cb[n], s[n], y);
        float zv = bf2f(zp[(size_t)t * D_MODEL]);
        yp[(size_t)t * D_MODEL] = f2bf(y * zv);
    }
}

extern "C" void kernel_launch(void* const* d_in, const int* in_sizes, int n_in,
                              void* d_out, int out_size, void* d_ws, size_t ws_size,
                              hipStream_t stream) {
    const float* x       = (const float*)d_in[0];
    const float* A_log   = (const float*)d_in[1];
    const float* B_param = (const float*)d_in[2];
    const float* C_param = (const float*)d_in[3];
    const float* log_dt  = (const float*)d_in[4];
    const float* in_w    = (const float*)d_in[5];
    const float* in_b    = (const float*)d_in[6];
    const float* out_w   = (const float*)d_in[7];
    const float* out_b   = (const float*)d_in[8];
    const float* ln_g    = (const float*)d_in[9];
    const float* ln_b    = (const float*)d_in[10];
    float* out = (float*)d_out;

    char* ws = (char*)d_ws;
    size_t off = 0;
    unsigned short* xn = (unsigned short*)(ws + off); off += (size_t)M_ROWS * D_MODEL * 2;        // 16 MB
    unsigned short* w1 = (unsigned short*)(ws + off); off += (size_t)2 * D_MODEL * D_MODEL * 2;   // 4 MB
    unsigned short* u  = (unsigned short*)(ws + off); off += (size_t)M_ROWS * D_MODEL * 2;        // 16 MB
    unsigned short* zs = (unsigned short*)(ws + off); off += (size_t)M_ROWS * D_MODEL * 2;        // 16 MB
    unsigned short* yz = (unsigned short*)(ws + off); off += (size_t)M_ROWS * D_MODEL * 2;        // 16 MB
    unsigned short* w2 = (unsigned short*)(ws + off); off += (size_t)D_MODEL * D_MODEL * 2;       // 2 MB
    float* s_local = (float*)(ws + off); off += (size_t)B_SZ * N_CHUNK * D_STATE * D_MODEL * 4;   // 8 MB
    float* s_init  = (float*)(ws + off); off += (size_t)B_SZ * N_CHUNK * D_STATE * D_MODEL * 4;   // 8 MB

    // weights -> bf16
    {
        int n4 = 2 * D_MODEL * D_MODEL / 4;
        conv_bf16_kernel<<<(n4 + 255) / 256, 256, 0, stream>>>(in_w, w1, n4);
    }
    {
        int n4 = D_MODEL * D_MODEL / 4;
        conv_bf16_kernel<<<(n4 + 255) / 256, 256, 0, stream>>>(out_w, w2, n4);
    }

    // layernorm
    ln_kernel<<<M_ROWS, 256, 0, stream>>>(x, ln_g, ln_b, xn);

    // GEMM1: (8192x1024) @ (2048x1024)^T -> u bf16 / silu(z) bf16
    gemm1_kernel<<<dim3(M_ROWS / 128, 2 * D_MODEL / 256), 256, 0, stream>>>(
        xn, w1, in_b, u, zs);

    // chunked SSM scan
    scan1_kernel<<<(B_SZ * N_CHUNK * D_MODEL) / 256, 256, 0, stream>>>(u, A_log, log_dt, s_local);
    scan_combine_kernel<<<(B_SZ * D_STATE * D_MODEL) / 256, 256, 0, stream>>>(s_local, A_log, log_dt, s_init);
    scan2_kernel<<<(B_SZ * N_CHUNK * D_MODEL) / 256, 256, 0, stream>>>(
        u, zs, A_log, B_param, C_param, log_dt, s_init, yz);

    // GEMM2: (8192x1024) @ (1024x1024)^T + resid, clip
    gemm2_kernel<<<dim3(M_ROWS / 128, D_MODEL / 128), 256, 0, stream>>>(
        yz, w2, out_b, out, x);
}